// Round 1
// baseline (8195.377 us; speedup 1.0000x reference)
//
#include <hip/hip_runtime.h>
#include <hip/hip_bf16.h>
#include <hip/hip_cooperative_groups.h>
#include <math.h>

// B=32, T=128, D_IN=32, H1=1024, H=2048, PEN=1024, C=64, P=4
// Inputs/outputs are FLOAT32 (per the reference dtypes; labels int32).
// Internally: f32 -> bf16 conversion at GEMM staging, bf16 MFMA compute,
// bf16 activations, f32 final outputs. Loose threshold (1.02e-2) admits bf16.

typedef __bf16 bf16_t;
typedef __bf16 bf16x8 __attribute__((ext_vector_type(8)));
typedef float  f32x4  __attribute__((ext_vector_type(4)));

static __device__ __forceinline__ void zero4(f32x4& v) {
  v[0] = 0.0f; v[1] = 0.0f; v[2] = 0.0f; v[3] = 0.0f;
}

template <typename T>
static __device__ __forceinline__ bf16x8 load8_as_bf16(const T* p);
template <>
__device__ __forceinline__ bf16x8 load8_as_bf16<bf16_t>(const bf16_t* p) {
  return *(const bf16x8*)p;
}
template <>
__device__ __forceinline__ bf16x8 load8_as_bf16<float>(const float* p) {
  bf16x8 v;
#pragma unroll
  for (int u = 0; u < 8; ++u) v[u] = (bf16_t)p[u];
  return v;
}

// ---------------------------------------------------------------------------
// GEMM: C[M,N] = act(A[M,K] * Bm[N,K]^T + bias[N]), row-major, bf16 C.
// A/B dtype templated (float inputs converted to bf16 at staging).
// 128x128 tile, BK=32, 256 threads = 4 waves 2x2, wave 64x64 via 4x4
// mfma_f32_16x16x32_bf16. Requires M%128==0, N%128==0, K%32==0.
// ---------------------------------------------------------------------------
template <typename TA, typename TB>
__global__ __launch_bounds__(256) void gemm_bt(
    const TA* __restrict__ A, const TB* __restrict__ Bm,
    const float* __restrict__ bias, bf16_t* __restrict__ C,
    int M, int N, int K, int relu)
{
  __shared__ __align__(16) bf16_t As[128 * 32];
  __shared__ __align__(16) bf16_t Bs[128 * 32];

  const int tid  = threadIdx.x;
  const int lane = tid & 63;
  const int wave = tid >> 6;
  const int q    = lane >> 4;     // quad 0..3
  const int l15  = lane & 15;
  const int wr   = wave >> 1;     // wave m-half
  const int wc   = wave & 1;      // wave n-half
  const int m0   = blockIdx.y * 128;
  const int n0   = blockIdx.x * 128;

  f32x4 acc[4][4];
#pragma unroll
  for (int i = 0; i < 4; ++i)
#pragma unroll
    for (int j = 0; j < 4; ++j) zero4(acc[i][j]);

  const int se = wave * 512 + lane * 8;  // element in a 2048-elem chunk

  const int kt_count = K >> 5;
  for (int kt = 0; kt < kt_count; ++kt) {
    const int k0 = kt << 5;

    bf16x8 av[2], bv[2];
#pragma unroll
    for (int c = 0; c < 2; ++c) {
      const int e   = c * 2048 + se;
      const int row = e >> 5;      // 0..127
      const int col = e & 31;      // 0,8,16,24
      av[c] = load8_as_bf16<TA>(&A [(size_t)(m0 + row) * K + k0 + col]);
      bv[c] = load8_as_bf16<TB>(&Bm[(size_t)(n0 + row) * K + k0 + col]);
    }

    __syncthreads();   // previous iteration's LDS reads complete
#pragma unroll
    for (int c = 0; c < 2; ++c) {
      *(bf16x8*)&As[c * 2048 + se] = av[c];
      *(bf16x8*)&Bs[c * 2048 + se] = bv[c];
    }
    __syncthreads();   // staging visible to all waves

    bf16x8 af[4], bfv[4];
#pragma unroll
    for (int i = 0; i < 4; ++i)
      af[i] = *(const bf16x8*)&As[(wr * 64 + i * 16 + l15) * 32 + q * 8];
#pragma unroll
    for (int j = 0; j < 4; ++j)
      bfv[j] = *(const bf16x8*)&Bs[(wc * 64 + j * 16 + l15) * 32 + q * 8];

#pragma unroll
    for (int i = 0; i < 4; ++i)
#pragma unroll
      for (int j = 0; j < 4; ++j)
        acc[i][j] = __builtin_amdgcn_mfma_f32_16x16x32_bf16(af[i], bfv[j], acc[i][j], 0, 0, 0);
  }

  // Epilogue: C/D layout col = lane&15 (n), row = (lane>>4)*4 + reg (m)
#pragma unroll
  for (int j = 0; j < 4; ++j) {
    const int n = n0 + wc * 64 + j * 16 + l15;
    const float bvl = bias[n];
#pragma unroll
    for (int i = 0; i < 4; ++i) {
      const int mbase = m0 + wr * 64 + i * 16 + q * 4;
#pragma unroll
      for (int r = 0; r < 4; ++r) {
        float v = acc[i][j][r] + bvl;
        if (relu) v = v > 0.0f ? v : 0.0f;
        C[(size_t)(mbase + r) * N + n] = (bf16_t)v;
      }
    }
  }
}

// ---------------------------------------------------------------------------
// Persistent GRU scan: ONE cooperative kernel does all 128 time steps.
// Grid = 256 WGs x 256 threads, 1 WG/CU (pinned by ~103 KB LDS).
// WG owns 8 h-columns j0..j0+7 -> W_hh rows {j0..}, {2048+j0..}, {4096+j0..}
// (r,z,n gates) = 24 rows x 2048 bf16 = 96 KB, LDS-RESIDENT for the whole
// scan (converted f32->bf16 at load; replaces the old cvt kernel + 24 MB
// W_hhb staging + 128x24MB L3 re-reads).
// Per step: 2x2 16x16x32 MFMA tiles (24 useful gate rows x batch 32),
// K=2048, A from LDS, B (hprev) from global (L2-resident 128 KB).
// Row stride padded +8 bf16 -> 2-way LDS bank alias only (free, m136).
// Each thread keeps its own h(b,jg) in a register for the z*h term.
// Cross-step visibility: store hs[t] -> __threadfence -> grid.sync().
// hs[t] addresses are written once then read (no stale-L1 hazard).
// ---------------------------------------------------------------------------
#define WROW 2056  // 2048 + 8 bf16 pad (16 B) -> 2-way bank alias, 16B aligned

__global__ __launch_bounds__(256, 1) void gru_persistent(
    const float* __restrict__ W_hh, const float* __restrict__ b_hh,
    const bf16_t* __restrict__ xp, bf16_t* __restrict__ hs)
{
  __shared__ __align__(16) bf16_t Ws[24 * WROW];   // 98,688 B
  __shared__ float hp_s[32][33];                   //  4,224 B

  const int tid  = threadIdx.x;
  const int lane = tid & 63;
  const int wave = tid >> 6;
  const int q    = lane >> 4;
  const int l15  = lane & 15;
  const int mt   = wave >> 1;   // m-tile (gate rows)
  const int nt   = wave & 1;    // n-tile (batch)
  const int j0   = blockIdx.x * 8;

  // ---- Stage this WG's W_hh slice into LDS once (f32 -> bf16) ----
  // Row m (0..23): gate = m>>3, source row = gate*2048 + j0 + (m&7).
  // 2048 f32 per row; 256 threads x 8 elems. Coalesced 32B/lane reads.
  for (int m = 0; m < 24; ++m) {
    const int gate = m >> 3;
    const float* src = W_hh + (size_t)(gate * 2048 + j0 + (m & 7)) * 2048;
    const int c = tid * 8;
    bf16x8 v;
#pragma unroll
    for (int u = 0; u < 8; ++u) v[u] = (bf16_t)src[c + u];
    *(bf16x8*)&Ws[m * WROW + c] = v;
  }

  // pointwise mapping: thread -> (batch b, local col jj)
  const int b  = tid >> 3;
  const int jj = tid & 7;
  const int jg = j0 + jj;
  const float bh_r = b_hh[jg];
  const float bh_z = b_hh[2048 + jg];
  const float bh_n = b_hh[4096 + jg];

  // matmul mapping: A row in LDS (rows 24..31 duplicate 16..23, discarded)
  const int m_local = mt * 16 + l15;
  const int ms = (m_local < 24) ? m_local : (16 + (m_local & 7));
  const bf16_t* arow = &Ws[ms * WROW];
  const int bcol = nt * 16 + l15;

  float hcur = 0.0f;   // this thread's own h(b, jg), kept in f32

  cooperative_groups::grid_group grid = cooperative_groups::this_grid();
  __syncthreads();     // Ws staged (block-local)

  for (int t = 0; t < 128; ++t) {
    // hoist xp gate loads: HBM latency hides under the matmul below
    const size_t xrow = (size_t)(b * 128 + t) * 6144;
    const float xr = (float)xp[xrow + jg];
    const float xz = (float)xp[xrow + 2048 + jg];
    const float xn = (float)xp[xrow + 4096 + jg];

    f32x4 acc; zero4(acc);
    if (t > 0) {
      const bf16_t* brow = hs + ((size_t)bcol * 128 + (t - 1)) * 2048;
      f32x4 ac0, ac1, ac2, ac3;
      zero4(ac0); zero4(ac1); zero4(ac2); zero4(ac3);
#pragma unroll 4
      for (int k = 0; k < 2048; k += 128) {
        bf16x8 a0 = *(const bf16x8*)&arow[k + q * 8];
        bf16x8 a1 = *(const bf16x8*)&arow[k + 32 + q * 8];
        bf16x8 a2 = *(const bf16x8*)&arow[k + 64 + q * 8];
        bf16x8 a3 = *(const bf16x8*)&arow[k + 96 + q * 8];
        bf16x8 b0 = *(const bf16x8*)&brow[k + q * 8];
        bf16x8 b1 = *(const bf16x8*)&brow[k + 32 + q * 8];
        bf16x8 b2 = *(const bf16x8*)&brow[k + 64 + q * 8];
        bf16x8 b3 = *(const bf16x8*)&brow[k + 96 + q * 8];
        ac0 = __builtin_amdgcn_mfma_f32_16x16x32_bf16(a0, b0, ac0, 0, 0, 0);
        ac1 = __builtin_amdgcn_mfma_f32_16x16x32_bf16(a1, b1, ac1, 0, 0, 0);
        ac2 = __builtin_amdgcn_mfma_f32_16x16x32_bf16(a2, b2, ac2, 0, 0, 0);
        ac3 = __builtin_amdgcn_mfma_f32_16x16x32_bf16(a3, b3, ac3, 0, 0, 0);
      }
      acc = (ac0 + ac1) + (ac2 + ac3);
    }

    // stage gate pre-activations: D row = q*4+r (gate row), col = batch
#pragma unroll
    for (int r = 0; r < 4; ++r) {
      const int ml = mt * 16 + q * 4 + r;
      if (ml < 24) hp_s[ml][bcol] = acc[r];
    }
    __syncthreads();

    const float hr = hp_s[jj][b]      + bh_r;
    const float hz = hp_s[8 + jj][b]  + bh_z;
    const float hn = hp_s[16 + jj][b] + bh_n;
    const float r_ = 1.0f / (1.0f + __expf(-(xr + hr)));
    const float z_ = 1.0f / (1.0f + __expf(-(xz + hz)));
    const float n_ = tanhf(xn + r_ * hn);
    hcur = (1.0f - z_) * n_ + z_ * hcur;
    hs[((size_t)b * 128 + t) * 2048 + jg] = (bf16_t)hcur;

    __threadfence();   // device-scope: push hs[t] past per-XCD L2
    grid.sync();       // all WGs see hs[t]; also covers hp_s reuse
  }
}

// ---------------------------------------------------------------------------
// Heads: per (b,t): 3 scalar heads + 4 sigmoid heads, 1024-dot each with a
// label-gathered f32 weight row. out_s is bf16, OUTPUT IS FLOAT32.
// ---------------------------------------------------------------------------
__global__ __launch_bounds__(256) void heads_kernel(
    const bf16_t* __restrict__ out_s, const int* __restrict__ labels,
    const float* __restrict__ W4, const float* __restrict__ b4,
    const float* __restrict__ W5, const float* __restrict__ b5,
    const float* __restrict__ W6, const float* __restrict__ b6,
    const float* __restrict__ Wp, const float* __restrict__ bp,
    float* __restrict__ out)
{
  const int bt  = blockIdx.x;
  const int b   = bt >> 7;         // T = 128
  const int lab = labels[b];
  const bf16_t* os  = out_s + (size_t)bt * 1024;
  const float* w4  = W4 + (size_t)lab * 1024;
  const float* w5  = W5 + (size_t)lab * 1024;
  const float* w6  = W6 + (size_t)lab * 1024;
  const float* wp0 = Wp + (size_t)lab * 1024;   // + p*65536 for plane p

  float s[7] = {0, 0, 0, 0, 0, 0, 0};
  for (int d = threadIdx.x; d < 1024; d += 256) {
    const float v = (float)os[d];
    s[0] += v * w4[d];
    s[1] += v * w5[d];
    s[2] += v * w6[d];
    s[3] += v * wp0[d];
    s[4] += v * wp0[65536 + d];
    s[5] += v * wp0[131072 + d];
    s[6] += v * wp0[196608 + d];
  }
#pragma unroll
  for (int i = 0; i < 7; ++i)
    for (int off = 32; off > 0; off >>= 1)
      s[i] += __shfl_down(s[i], off, 64);

  __shared__ float red[4][7];
  const int lane = threadIdx.x & 63, wave = threadIdx.x >> 6;
  if (lane == 0)
    for (int i = 0; i < 7; ++i) red[wave][i] = s[i];
  __syncthreads();
  if (threadIdx.x == 0) {
    float tsum[7];
    for (int i = 0; i < 7; ++i)
      tsum[i] = red[0][i] + red[1][i] + red[2][i] + red[3][i];
    out[bt]        = tsum[0] + b4[lab];
    out[4096 + bt] = tsum[1] + b5[lab];
    out[8192 + bt] = tsum[2] + b6[lab];
#pragma unroll
    for (int p = 0; p < 4; ++p) {
      const float v = tsum[3 + p] + bp[p * 64 + lab];
      out[12288 + p * 4096 + bt] = 1.0f / (1.0f + __expf(-v));
    }
  }
}

// ---------------------------------------------------------------------------
extern "C" void kernel_launch(void* const* d_in, const int* in_sizes, int n_in,
                              void* d_out, int out_size, void* d_ws, size_t ws_size,
                              hipStream_t stream)
{
  const float* x     = (const float*)d_in[0];
  const int*   label = (const int*)d_in[1];
  const float* W1    = (const float*)d_in[2];
  const float* b1    = (const float*)d_in[3];
  const float* W2    = (const float*)d_in[4];
  const float* b2    = (const float*)d_in[5];
  const float* W_ih  = (const float*)d_in[6];
  const float* b_ih  = (const float*)d_in[7];
  const float* W_hh  = (const float*)d_in[8];
  const float* b_hh  = (const float*)d_in[9];
  const float* W3    = (const float*)d_in[10];
  const float* b3    = (const float*)d_in[11];
  const float* W4    = (const float*)d_in[12];
  const float* b4    = (const float*)d_in[13];
  const float* W5    = (const float*)d_in[14];
  const float* b5    = (const float*)d_in[15];
  const float* W6    = (const float*)d_in[16];
  const float* b6    = (const float*)d_in[17];
  const float* Wp    = (const float*)d_in[18];
  const float* bp    = (const float*)d_in[19];

  // Workspace (96 MB peak), bf16 internals:
  //   out1  [24,32MB)  4096x1024  — dead after layer2
  //   out2  [32,48MB)  4096x2048  — dead after xp GEMM
  //   xp    [48,96MB)  4096x6144  — live through GRU
  //   hs    [24,40MB)  (B,T,2048) — overlays out1+out2-head (dead)
  //   out_s [40,48MB)  4096x1024  — overlays out2 tail (dead)
  // ([0,24MB) was the old W_hhb staging; W_hh now goes straight to LDS.)
  char* ws = (char*)d_ws;
  bf16_t* out1  = (bf16_t*)(ws + (24u << 20));
  bf16_t* out2  = (bf16_t*)(ws + (32u << 20));
  bf16_t* xp    = (bf16_t*)(ws + (48u << 20));
  bf16_t* hs    = (bf16_t*)(ws + (24u << 20));
  bf16_t* out_s = (bf16_t*)(ws + (40u << 20));
  float*  outp  = (float*)d_out;

  hipMemsetAsync(d_out, 0, (size_t)out_size * sizeof(float), stream);

  dim3 blk(256);
  // layer1: (4096x32)*(1024x32)^T, relu
  gemm_bt<float, float><<<dim3(8, 32), blk, 0, stream>>>(x, W1, b1, out1, 4096, 1024, 32, 1);
  // layer2: (4096x1024)*(2048x1024)^T, relu
  gemm_bt<bf16_t, float><<<dim3(16, 32), blk, 0, stream>>>(out1, W2, b2, out2, 4096, 2048, 1024, 1);
  // xp: (4096x2048)*(6144x2048)^T + b_ih
  gemm_bt<bf16_t, float><<<dim3(48, 32), blk, 0, stream>>>(out2, W_ih, b_ih, xp, 4096, 6144, 2048, 0);
  // GRU scan: single persistent cooperative kernel, grid-synced per step
  {
    void* gru_args[] = { (void*)&W_hh, (void*)&b_hh, (void*)&xp, (void*)&hs };
    hipLaunchCooperativeKernel((void*)gru_persistent, dim3(256), blk,
                               gru_args, 0, stream);
  }
  // layer3: (4096x2048)*(1024x2048)^T, relu
  gemm_bt<bf16_t, float><<<dim3(8, 32), blk, 0, stream>>>(hs, W3, b3, out_s, 4096, 1024, 2048, 1);
  // heads (f32 weights, f32 out)
  heads_kernel<<<dim3(4096), blk, 0, stream>>>(out_s, label, W4, b4, W5, b5, W6, b6, Wp, bp, outp);
}

// Round 2
// 1801.746 us; speedup vs baseline: 4.5486x; 4.5486x over previous
//
#include <hip/hip_runtime.h>
#include <hip/hip_bf16.h>
#include <hip/hip_cooperative_groups.h>
#include <math.h>

// B=32, T=128, D_IN=32, H1=1024, H=2048, PEN=1024, C=64, P=4
// Inputs/outputs are FLOAT32 (per the reference dtypes; labels int32).
// Internally: f32 -> bf16 conversion at GEMM staging, bf16 MFMA compute,
// bf16 activations, f32 final outputs. Loose threshold (1.02e-2) admits bf16.

typedef __bf16 bf16_t;
typedef __bf16 bf16x8 __attribute__((ext_vector_type(8)));
typedef float  f32x4  __attribute__((ext_vector_type(4)));

static __device__ __forceinline__ void zero4(f32x4& v) {
  v[0] = 0.0f; v[1] = 0.0f; v[2] = 0.0f; v[3] = 0.0f;
}

template <typename T>
static __device__ __forceinline__ bf16x8 load8_as_bf16(const T* p);
template <>
__device__ __forceinline__ bf16x8 load8_as_bf16<bf16_t>(const bf16_t* p) {
  return *(const bf16x8*)p;
}
template <>
__device__ __forceinline__ bf16x8 load8_as_bf16<float>(const float* p) {
  bf16x8 v;
#pragma unroll
  for (int u = 0; u < 8; ++u) v[u] = (bf16_t)p[u];
  return v;
}

// ---------------------------------------------------------------------------
// GEMM: C[M,N] = act(A[M,K] * Bm[N,K]^T + bias[N]), row-major, bf16 C.
// (unchanged from the 2618us baseline)
// ---------------------------------------------------------------------------
template <typename TA, typename TB>
__global__ __launch_bounds__(256) void gemm_bt(
    const TA* __restrict__ A, const TB* __restrict__ Bm,
    const float* __restrict__ bias, bf16_t* __restrict__ C,
    int M, int N, int K, int relu)
{
  __shared__ __align__(16) bf16_t As[128 * 32];
  __shared__ __align__(16) bf16_t Bs[128 * 32];

  const int tid  = threadIdx.x;
  const int lane = tid & 63;
  const int wave = tid >> 6;
  const int q    = lane >> 4;     // quad 0..3
  const int l15  = lane & 15;
  const int wr   = wave >> 1;     // wave m-half
  const int wc   = wave & 1;      // wave n-half
  const int m0   = blockIdx.y * 128;
  const int n0   = blockIdx.x * 128;

  f32x4 acc[4][4];
#pragma unroll
  for (int i = 0; i < 4; ++i)
#pragma unroll
    for (int j = 0; j < 4; ++j) zero4(acc[i][j]);

  const int se = wave * 512 + lane * 8;  // element in a 2048-elem chunk

  const int kt_count = K >> 5;
  for (int kt = 0; kt < kt_count; ++kt) {
    const int k0 = kt << 5;

    bf16x8 av[2], bv[2];
#pragma unroll
    for (int c = 0; c < 2; ++c) {
      const int e   = c * 2048 + se;
      const int row = e >> 5;      // 0..127
      const int col = e & 31;      // 0,8,16,24
      av[c] = load8_as_bf16<TA>(&A [(size_t)(m0 + row) * K + k0 + col]);
      bv[c] = load8_as_bf16<TB>(&Bm[(size_t)(n0 + row) * K + k0 + col]);
    }

    __syncthreads();   // previous iteration's LDS reads complete
#pragma unroll
    for (int c = 0; c < 2; ++c) {
      *(bf16x8*)&As[c * 2048 + se] = av[c];
      *(bf16x8*)&Bs[c * 2048 + se] = bv[c];
    }
    __syncthreads();   // staging visible to all waves

    bf16x8 af[4], bfv[4];
#pragma unroll
    for (int i = 0; i < 4; ++i)
      af[i] = *(const bf16x8*)&As[(wr * 64 + i * 16 + l15) * 32 + q * 8];
#pragma unroll
    for (int j = 0; j < 4; ++j)
      bfv[j] = *(const bf16x8*)&Bs[(wc * 64 + j * 16 + l15) * 32 + q * 8];

#pragma unroll
    for (int i = 0; i < 4; ++i)
#pragma unroll
      for (int j = 0; j < 4; ++j)
        acc[i][j] = __builtin_amdgcn_mfma_f32_16x16x32_bf16(af[i], bfv[j], acc[i][j], 0, 0, 0);
  }

  // Epilogue: C/D layout col = lane&15 (n), row = (lane>>4)*4 + reg (m)
#pragma unroll
  for (int j = 0; j < 4; ++j) {
    const int n = n0 + wc * 64 + j * 16 + l15;
    const float bvl = bias[n];
#pragma unroll
    for (int i = 0; i < 4; ++i) {
      const int mbase = m0 + wr * 64 + i * 16 + q * 4;
#pragma unroll
      for (int r = 0; r < 4; ++r) {
        float v = acc[i][j][r] + bvl;
        if (relu) v = v > 0.0f ? v : 0.0f;
        C[(size_t)(mbase + r) * N + n] = (bf16_t)v;
      }
    }
  }
}

// ---------------------------------------------------------------------------
// Persistent GRU scan, round 2.
// Round-1 post-mortem: grid.sync()+threadfence = ~50us/step of L2
// writeback/invalidate + slow CG spin (MfmaUtil 0.7%, VALUBusy 0.8%).
// This version has ZERO cache-maintenance instructions:
//   - hs[t] stores: relaxed agent-scope atomic u32 stores (sc0 sc1,
//     write-through to LLC, no L2 dirty lines). Lane pairs pack 2 bf16
//     via shfl_xor.
//   - barrier: 128 pre-zeroed counters in ws; 1 relaxed agent-scope
//     atomicAdd per WG per step (executes at LLC), spin on relaxed
//     agent-scope load + s_sleep. No generation reset, no fences.
//   - hs[t-1] reads: PLAIN loads. Safe: each hs line is read only after
//     the step-(t-1) barrier proved the write-through reached LLC, t is
//     monotonic so no address is ever re-read, and local L2 never holds
//     a stale copy (stores are no-allocate write-through; kernel-start
//     acquire invalidated GEMM leftovers).
// Work split: 4 waves each own a K-QUARTER (512) and compute the full
// 24x32 gate block; partials reduced through LDS. vs round-1's tile
// split this halves LLC line requests (each of the 2048 hprev lines per
// CU fetched exactly once per step) and gives 4 independent load streams.
// W_hh slice (24 rows x 2048 bf16, padded) stays LDS-resident all scan.
// ---------------------------------------------------------------------------
#define WROW 2056  // 2048 + 8 bf16 pad (16 B) -> 2-way bank alias only

__global__ __launch_bounds__(256, 1) void gru_persistent(
    const float* __restrict__ W_hh, const float* __restrict__ b_hh,
    const bf16_t* __restrict__ xp, bf16_t* __restrict__ hs,
    unsigned* __restrict__ bar)
{
  __shared__ __align__(16) bf16_t Ws[24 * WROW];   // 98,688 B
  __shared__ float hp_p[4][24][33];                // 12,672 B partials

  const int tid  = threadIdx.x;
  const int lane = tid & 63;
  const int wave = tid >> 6;      // = K-quarter owner
  const int q    = lane >> 4;
  const int l15  = lane & 15;
  const int j0   = blockIdx.x * 8;

  // ---- Stage this WG's W_hh slice into LDS once (f32 -> bf16) ----
  for (int m = 0; m < 24; ++m) {
    const int gate = m >> 3;
    const float* src = W_hh + (size_t)(gate * 2048 + j0 + (m & 7)) * 2048;
    const int c = tid * 8;
    bf16x8 v;
#pragma unroll
    for (int u = 0; u < 8; ++u) v[u] = (bf16_t)src[c + u];
    *(bf16x8*)&Ws[m * WROW + c] = v;
  }

  // pointwise mapping: thread -> (batch b, local col jj)
  const int b  = tid >> 3;
  const int jj = tid & 7;
  const int jg = j0 + jj;
  const float bh_r = b_hh[jg];
  const float bh_z = b_hh[2048 + jg];
  const float bh_n = b_hh[4096 + jg];

  // matmul mapping: wave owns k in [wave*512, wave*512+512)
  const int k0w = wave * 512;
  const int ms0 = l15;                                         // rows 0..15
  const int ms1 = (l15 < 8) ? (16 + l15) : (16 + (l15 & 7));   // 16..23 (+dup)
  const bf16_t* arow0 = &Ws[(size_t)ms0 * WROW + k0w];
  const bf16_t* arow1 = &Ws[(size_t)ms1 * WROW + k0w];
  const int bc0 = l15;          // batch tile 0
  const int bc1 = 16 + l15;     // batch tile 1

  float hcur = 0.0f;            // this thread's own h(b, jg)
  unsigned* hs32 = (unsigned*)hs;

  __syncthreads();              // Ws staged (block-local only)

  for (int t = 0; t < 128; ++t) {
    // hoist xp gate loads: latency hides under the matmul
    const size_t xrow = (size_t)(b * 128 + t) * 6144;
    const float xr = (float)xp[xrow + jg];
    const float xz = (float)xp[xrow + 2048 + jg];
    const float xn = (float)xp[xrow + 4096 + jg];

    if (t > 0) {
      const bf16_t* brow0 = hs + ((size_t)bc0 * 128 + (t - 1)) * 2048 + k0w;
      const bf16_t* brow1 = hs + ((size_t)bc1 * 128 + (t - 1)) * 2048 + k0w;
      f32x4 a00, a01, a10, a11;
      zero4(a00); zero4(a01); zero4(a10); zero4(a11);
#pragma unroll 4
      for (int k = 0; k < 512; k += 32) {
        bf16x8 A0 = *(const bf16x8*)&arow0[k + q * 8];
        bf16x8 A1 = *(const bf16x8*)&arow1[k + q * 8];
        bf16x8 B0 = *(const bf16x8*)&brow0[k + q * 8];
        bf16x8 B1 = *(const bf16x8*)&brow1[k + q * 8];
        a00 = __builtin_amdgcn_mfma_f32_16x16x32_bf16(A0, B0, a00, 0, 0, 0);
        a01 = __builtin_amdgcn_mfma_f32_16x16x32_bf16(A0, B1, a01, 0, 0, 0);
        a10 = __builtin_amdgcn_mfma_f32_16x16x32_bf16(A1, B0, a10, 0, 0, 0);
        a11 = __builtin_amdgcn_mfma_f32_16x16x32_bf16(A1, B1, a11, 0, 0, 0);
      }
      // partials: D col = lane&15 (batch), row = q*4+reg (gate row)
#pragma unroll
      for (int r = 0; r < 4; ++r) {
        const int gr0 = q * 4 + r;          // rows 0..15, all valid
        hp_p[wave][gr0][l15]      = a00[r];
        hp_p[wave][gr0][16 + l15] = a01[r];
        const int gr1 = 16 + q * 4 + r;     // rows 16..31, keep <24
        if (gr1 < 24) {
          hp_p[wave][gr1][l15]      = a10[r];
          hp_p[wave][gr1][16 + l15] = a11[r];
        }
      }
    }
    __syncthreads();   // partials visible (and prev pointwise done)

    float pr = 0.0f, pz = 0.0f, pn = 0.0f;
    if (t > 0) {
#pragma unroll
      for (int w = 0; w < 4; ++w) {
        pr += hp_p[w][jj][b];
        pz += hp_p[w][8 + jj][b];
        pn += hp_p[w][16 + jj][b];
      }
    }
    const float hr = pr + bh_r;
    const float hz = pz + bh_z;
    const float hn = pn + bh_n;
    const float r_ = 1.0f / (1.0f + __expf(-(xr + hr)));
    const float z_ = 1.0f / (1.0f + __expf(-(xz + hz)));
    const float n_ = tanhf(xn + r_ * hn);
    hcur = (1.0f - z_) * n_ + z_ * hcur;

    // pack lane-pair (jj even/odd share b) into u32, agent-scope store
    union { bf16_t h; unsigned short u; } cv; cv.h = (bf16_t)hcur;
    const unsigned hv = cv.u;
    const unsigned ov = (unsigned)__shfl_xor((int)hv, 1, 64);
    if ((tid & 1) == 0) {
      const unsigned pk = hv | (ov << 16);
      const size_t widx = ((size_t)b * 128 + t) * 1024 + (jg >> 1);
      __hip_atomic_store(hs32 + widx, pk, __ATOMIC_RELAXED,
                         __HIP_MEMORY_SCOPE_AGENT);
    }

    // ---- lightweight grid barrier (no cache maintenance) ----
    if (t < 127) {
      asm volatile("s_waitcnt vmcnt(0)" ::: "memory");  // h stores at LLC
      __syncthreads();                                  // whole WG done
      if (tid == 0) {
        unsigned* slot = bar + t;
        const unsigned prev = __hip_atomic_fetch_add(
            slot, 1u, __ATOMIC_RELAXED, __HIP_MEMORY_SCOPE_AGENT);
        if (prev != 255u) {
          int guard = 0;
          while (__hip_atomic_load(slot, __ATOMIC_RELAXED,
                                   __HIP_MEMORY_SCOPE_AGENT) < 256u) {
            __builtin_amdgcn_s_sleep(2);
            if (++guard > (1 << 20)) break;   // safety: never hang
          }
        }
      }
      __syncthreads();   // release WG; next step may read hs[t]
    }
  }
}

// ---------------------------------------------------------------------------
// Heads: per (b,t): 3 scalar heads + 4 sigmoid heads, 1024-dot each with a
// label-gathered f32 weight row. out_s is bf16, OUTPUT IS FLOAT32.
// ---------------------------------------------------------------------------
__global__ __launch_bounds__(256) void heads_kernel(
    const bf16_t* __restrict__ out_s, const int* __restrict__ labels,
    const float* __restrict__ W4, const float* __restrict__ b4,
    const float* __restrict__ W5, const float* __restrict__ b5,
    const float* __restrict__ W6, const float* __restrict__ b6,
    const float* __restrict__ Wp, const float* __restrict__ bp,
    float* __restrict__ out)
{
  const int bt  = blockIdx.x;
  const int b   = bt >> 7;         // T = 128
  const int lab = labels[b];
  const bf16_t* os  = out_s + (size_t)bt * 1024;
  const float* w4  = W4 + (size_t)lab * 1024;
  const float* w5  = W5 + (size_t)lab * 1024;
  const float* w6  = W6 + (size_t)lab * 1024;
  const float* wp0 = Wp + (size_t)lab * 1024;   // + p*65536 for plane p

  float s[7] = {0, 0, 0, 0, 0, 0, 0};
  for (int d = threadIdx.x; d < 1024; d += 256) {
    const float v = (float)os[d];
    s[0] += v * w4[d];
    s[1] += v * w5[d];
    s[2] += v * w6[d];
    s[3] += v * wp0[d];
    s[4] += v * wp0[65536 + d];
    s[5] += v * wp0[131072 + d];
    s[6] += v * wp0[196608 + d];
  }
#pragma unroll
  for (int i = 0; i < 7; ++i)
    for (int off = 32; off > 0; off >>= 1)
      s[i] += __shfl_down(s[i], off, 64);

  __shared__ float red[4][7];
  const int lane = threadIdx.x & 63, wave = threadIdx.x >> 6;
  if (lane == 0)
    for (int i = 0; i < 7; ++i) red[wave][i] = s[i];
  __syncthreads();
  if (threadIdx.x == 0) {
    float tsum[7];
    for (int i = 0; i < 7; ++i)
      tsum[i] = red[0][i] + red[1][i] + red[2][i] + red[3][i];
    out[bt]        = tsum[0] + b4[lab];
    out[4096 + bt] = tsum[1] + b5[lab];
    out[8192 + bt] = tsum[2] + b6[lab];
#pragma unroll
    for (int p = 0; p < 4; ++p) {
      const float v = tsum[3 + p] + bp[p * 64 + lab];
      out[12288 + p * 4096 + bt] = 1.0f / (1.0f + __expf(-v));
    }
  }
}

// ---------------------------------------------------------------------------
extern "C" void kernel_launch(void* const* d_in, const int* in_sizes, int n_in,
                              void* d_out, int out_size, void* d_ws, size_t ws_size,
                              hipStream_t stream)
{
  const float* x     = (const float*)d_in[0];
  const int*   label = (const int*)d_in[1];
  const float* W1    = (const float*)d_in[2];
  const float* b1    = (const float*)d_in[3];
  const float* W2    = (const float*)d_in[4];
  const float* b2    = (const float*)d_in[5];
  const float* W_ih  = (const float*)d_in[6];
  const float* b_ih  = (const float*)d_in[7];
  const float* W_hh  = (const float*)d_in[8];
  const float* b_hh  = (const float*)d_in[9];
  const float* W3    = (const float*)d_in[10];
  const float* b3    = (const float*)d_in[11];
  const float* W4    = (const float*)d_in[12];
  const float* b4    = (const float*)d_in[13];
  const float* W5    = (const float*)d_in[14];
  const float* b5    = (const float*)d_in[15];
  const float* W6    = (const float*)d_in[16];
  const float* b6    = (const float*)d_in[17];
  const float* Wp    = (const float*)d_in[18];
  const float* bp    = (const float*)d_in[19];

  // Workspace map (96 MB), bf16 internals:
  //   bar   [0, 4KB)   128 u32 per-step barrier counters (memset 0)
  //   out1  [24,32MB)  4096x1024  — dead after layer2
  //   out2  [32,48MB)  4096x2048  — dead after xp GEMM
  //   xp    [48,96MB)  4096x6144  — live through GRU
  //   hs    [24,40MB)  (B,T,2048) — overlays out1+out2-head (dead)
  //   out_s [40,48MB)  4096x1024  — overlays out2 tail (dead)
  char* ws = (char*)d_ws;
  unsigned* bar = (unsigned*)ws;
  bf16_t* out1  = (bf16_t*)(ws + (24u << 20));
  bf16_t* out2  = (bf16_t*)(ws + (32u << 20));
  bf16_t* xp    = (bf16_t*)(ws + (48u << 20));
  bf16_t* hs    = (bf16_t*)(ws + (24u << 20));
  bf16_t* out_s = (bf16_t*)(ws + (40u << 20));
  float*  outp  = (float*)d_out;

  hipMemsetAsync(d_out, 0, (size_t)out_size * sizeof(float), stream);
  hipMemsetAsync(ws, 0, 4096, stream);   // barrier counters

  dim3 blk(256);
  // layer1: (4096x32)*(1024x32)^T, relu
  gemm_bt<float, float><<<dim3(8, 32), blk, 0, stream>>>(x, W1, b1, out1, 4096, 1024, 32, 1);
  // layer2: (4096x1024)*(2048x1024)^T, relu
  gemm_bt<bf16_t, float><<<dim3(16, 32), blk, 0, stream>>>(out1, W2, b2, out2, 4096, 2048, 1024, 1);
  // xp: (4096x2048)*(6144x2048)^T + b_ih
  gemm_bt<bf16_t, float><<<dim3(48, 32), blk, 0, stream>>>(out2, W_ih, b_ih, xp, 4096, 6144, 2048, 0);
  // GRU scan: persistent cooperative kernel, custom per-step barrier
  {
    void* gru_args[] = { (void*)&W_hh, (void*)&b_hh, (void*)&xp, (void*)&hs,
                         (void*)&bar };
    hipLaunchCooperativeKernel((void*)gru_persistent, dim3(256), blk,
                               gru_args, 0, stream);
  }
  // layer3: (4096x2048)*(1024x2048)^T, relu
  gemm_bt<bf16_t, float><<<dim3(8, 32), blk, 0, stream>>>(hs, W3, b3, out_s, 4096, 1024, 2048, 1);
  // heads (f32 weights, f32 out)
  heads_kernel<<<dim3(4096), blk, 0, stream>>>(out_s, label, W4, b4, W5, b5, W6, b6, Wp, bp, outp);
}

// Round 3
// 1453.430 us; speedup vs baseline: 5.6386x; 1.2397x over previous
//
#include <hip/hip_runtime.h>
#include <hip/hip_bf16.h>
#include <math.h>

// B=32, T=128, D_IN=32, H1=1024, H=2048, PEN=1024, C=64, P=4
// Inputs/outputs are FLOAT32 (per the reference dtypes; labels int32).
// Internally: f32 -> bf16 conversion at GEMM staging, bf16 MFMA compute,
// bf16 activations, f32 final outputs. Loose threshold (1.02e-2) admits bf16.

typedef __bf16 bf16_t;
typedef __bf16 bf16x8 __attribute__((ext_vector_type(8)));
typedef float  f32x4  __attribute__((ext_vector_type(4)));

static __device__ __forceinline__ void zero4(f32x4& v) {
  v[0] = 0.0f; v[1] = 0.0f; v[2] = 0.0f; v[3] = 0.0f;
}

template <typename T>
static __device__ __forceinline__ bf16x8 load8_as_bf16(const T* p);
template <>
__device__ __forceinline__ bf16x8 load8_as_bf16<bf16_t>(const bf16_t* p) {
  return *(const bf16x8*)p;
}
template <>
__device__ __forceinline__ bf16x8 load8_as_bf16<float>(const float* p) {
  bf16x8 v;
#pragma unroll
  for (int u = 0; u < 8; ++u) v[u] = (bf16_t)p[u];
  return v;
}

// ---------------------------------------------------------------------------
// GEMM: C[M,N] = act(A[M,K] * Bm[N,K]^T + bias[N]), row-major, bf16 C.
// (unchanged from the 2618us baseline)
// ---------------------------------------------------------------------------
template <typename TA, typename TB>
__global__ __launch_bounds__(256) void gemm_bt(
    const TA* __restrict__ A, const TB* __restrict__ Bm,
    const float* __restrict__ bias, bf16_t* __restrict__ C,
    int M, int N, int K, int relu)
{
  __shared__ __align__(16) bf16_t As[128 * 32];
  __shared__ __align__(16) bf16_t Bs[128 * 32];

  const int tid  = threadIdx.x;
  const int lane = tid & 63;
  const int wave = tid >> 6;
  const int q    = lane >> 4;     // quad 0..3
  const int l15  = lane & 15;
  const int wr   = wave >> 1;     // wave m-half
  const int wc   = wave & 1;      // wave n-half
  const int m0   = blockIdx.y * 128;
  const int n0   = blockIdx.x * 128;

  f32x4 acc[4][4];
#pragma unroll
  for (int i = 0; i < 4; ++i)
#pragma unroll
    for (int j = 0; j < 4; ++j) zero4(acc[i][j]);

  const int se = wave * 512 + lane * 8;  // element in a 2048-elem chunk

  const int kt_count = K >> 5;
  for (int kt = 0; kt < kt_count; ++kt) {
    const int k0 = kt << 5;

    bf16x8 av[2], bv[2];
#pragma unroll
    for (int c = 0; c < 2; ++c) {
      const int e   = c * 2048 + se;
      const int row = e >> 5;      // 0..127
      const int col = e & 31;      // 0,8,16,24
      av[c] = load8_as_bf16<TA>(&A [(size_t)(m0 + row) * K + k0 + col]);
      bv[c] = load8_as_bf16<TB>(&Bm[(size_t)(n0 + row) * K + k0 + col]);
    }

    __syncthreads();   // previous iteration's LDS reads complete
#pragma unroll
    for (int c = 0; c < 2; ++c) {
      *(bf16x8*)&As[c * 2048 + se] = av[c];
      *(bf16x8*)&Bs[c * 2048 + se] = bv[c];
    }
    __syncthreads();   // staging visible to all waves

    bf16x8 af[4], bfv[4];
#pragma unroll
    for (int i = 0; i < 4; ++i)
      af[i] = *(const bf16x8*)&As[(wr * 64 + i * 16 + l15) * 32 + q * 8];
#pragma unroll
    for (int j = 0; j < 4; ++j)
      bfv[j] = *(const bf16x8*)&Bs[(wc * 64 + j * 16 + l15) * 32 + q * 8];

#pragma unroll
    for (int i = 0; i < 4; ++i)
#pragma unroll
      for (int j = 0; j < 4; ++j)
        acc[i][j] = __builtin_amdgcn_mfma_f32_16x16x32_bf16(af[i], bfv[j], acc[i][j], 0, 0, 0);
  }

  // Epilogue: C/D layout col = lane&15 (n), row = (lane>>4)*4 + reg (m)
#pragma unroll
  for (int j = 0; j < 4; ++j) {
    const int n = n0 + wc * 64 + j * 16 + l15;
    const float bvl = bias[n];
#pragma unroll
    for (int i = 0; i < 4; ++i) {
      const int mbase = m0 + wr * 64 + i * 16 + q * 4;
#pragma unroll
      for (int r = 0; r < 4; ++r) {
        float v = acc[i][j][r] + bvl;
        if (relu) v = v > 0.0f ? v : 0.0f;
        C[(size_t)(mbase + r) * N + n] = (bf16_t)v;
      }
    }
  }
}

// ---------------------------------------------------------------------------
// Persistent GRU scan, round 3.
// Round-2 post-mortem: 10.5us/step at 1 wave/SIMD — all latency (hprev LLC
// fetch, store drain, contended-atomic barrier) serialized; 29M LDS bank
// conflict cycles from Ws/hp_p.
// Round-3 structure:
//  - 128 WGs x 512 threads (8 waves = 2 waves/SIMD -> TLP). WG owns 16
//    h-columns -> 48 gate rows = EXACTLY 3 MFMA row-tiles (gate = tile).
//  - W_hh slice lives in REGISTERS: wave w owns K-slice [w*256,(w+1)*256);
//    3 row-tiles x 8 k-windows = 24 bf16x8 frags = 96 VGPR/lane, loaded
//    once (f32->bf16). No LDS A-reads at all.
//  - Per step per wave: 16 independent global B-loads (hprev frags, one
//    burst, 64 VGPRs in flight) -> 48 MFMA -> 6 ds_write_b128 partials
//    (pad 52: conflict-free) -> pointwise (24 scalar LDS reads).
//  - hs[t] stores: relaxed agent-scope u32 atomic stores (write-through
//    past per-XCD L2; readers' plain loads never see stale L2 lines since
//    L2 was invalidated at kernel start and these addrs are only ever
//    filled by post-barrier reads of final data).
//  - Barrier: contention-free. WG i stores flag arr[t*128+i] (parallel
//    plain atomic stores, no RMW). Wave 0 of every WG polls all 128 flags
//    (2/lane + __all). xp[t+1] prefetch issued before the spin so its LLC
//    latency hides under the barrier wait.
// ---------------------------------------------------------------------------
__global__ __launch_bounds__(512, 2) void gru_persistent(
    const float* __restrict__ W_hh, const float* __restrict__ b_hh,
    const bf16_t* __restrict__ xp, bf16_t* __restrict__ hs,
    unsigned* __restrict__ arr)
{
  __shared__ __align__(16) float hp_p[8][32][52];   // 53,248 B partials

  const int tid  = threadIdx.x;
  const int lane = tid & 63;
  const int wave = tid >> 6;      // K-slice owner, 0..7
  const int q    = lane >> 4;
  const int l15  = lane & 15;
  const int j0   = blockIdx.x * 16;
  const int k0w  = wave * 256;

  // ---- Preload W_hh slice into registers (f32 -> bf16), once ----
  // frag[rt][win]: lane (l15,q): row rt*2048 + j0 + l15 (rt == gate),
  // k = k0w + win*32 + q*8 .. +8
  bf16x8 wf[3][8];
#pragma unroll
  for (int rt = 0; rt < 3; ++rt) {
    const float* rp = W_hh + ((size_t)(rt * 2048 + j0 + l15)) * 2048 + k0w;
#pragma unroll
    for (int win = 0; win < 8; ++win)
      wf[rt][win] = load8_as_bf16<float>(rp + win * 32 + q * 8);
  }

  // pointwise mapping: thread -> (batch b, local col jj)
  const int b  = tid >> 4;        // 0..31
  const int jj = tid & 15;        // 0..15
  const int jg = j0 + jj;
  const float bh_r = b_hh[jg];
  const float bh_z = b_hh[2048 + jg];
  const float bh_n = b_hh[4096 + jg];

  float hcur = 0.0f;              // this thread's own h(b, jg)
  unsigned* hs32 = (unsigned*)hs;

  // xp for t=0
  float xr_c = (float)xp[(size_t)(b * 128 + 0) * 6144 + jg];
  float xz_c = (float)xp[(size_t)(b * 128 + 0) * 6144 + 2048 + jg];
  float xn_c = (float)xp[(size_t)(b * 128 + 0) * 6144 + 4096 + jg];

  for (int t = 0; t < 128; ++t) {
    if (t > 0) {
      // ---- hprev fragment burst: 16 independent 16B loads ----
      bf16x8 bfr[2][8];
#pragma unroll
      for (int ct = 0; ct < 2; ++ct) {
        const bf16_t* bp_ = hs + ((size_t)(ct * 16 + l15) * 128 + (t - 1)) * 2048
                               + k0w + q * 8;
#pragma unroll
        for (int win = 0; win < 8; ++win)
          bfr[ct][win] = *(const bf16x8*)(bp_ + win * 32);
      }

      f32x4 acc[3][2];
#pragma unroll
      for (int rt = 0; rt < 3; ++rt)
#pragma unroll
        for (int ct = 0; ct < 2; ++ct) zero4(acc[rt][ct]);

#pragma unroll
      for (int win = 0; win < 8; ++win)
#pragma unroll
        for (int rt = 0; rt < 3; ++rt)
#pragma unroll
          for (int ct = 0; ct < 2; ++ct)
            acc[rt][ct] = __builtin_amdgcn_mfma_f32_16x16x32_bf16(
                wf[rt][win], bfr[ct][win], acc[rt][ct], 0, 0, 0);

      // partials: D col = l15 (batch within ct-tile), row = q*4+reg (col jj)
#pragma unroll
      for (int rt = 0; rt < 3; ++rt)
#pragma unroll
        for (int ct = 0; ct < 2; ++ct)
          *(f32x4*)&hp_p[wave][ct * 16 + l15][rt * 16 + q * 4] = acc[rt][ct];
    }
    __syncthreads();   // partials visible (and prev-step LDS reuse safe)

    float pr = 0.0f, pz = 0.0f, pn = 0.0f;
    if (t > 0) {
#pragma unroll
      for (int w = 0; w < 8; ++w) {
        pr += hp_p[w][b][jj];
        pz += hp_p[w][b][16 + jj];
        pn += hp_p[w][b][32 + jj];
      }
    }
    const float r_ = 1.0f / (1.0f + __expf(-(xr_c + pr + bh_r)));
    const float z_ = 1.0f / (1.0f + __expf(-(xz_c + pz + bh_z)));
    const float n_ = tanhf(xn_c + r_ * (pn + bh_n));
    hcur = (1.0f - z_) * n_ + z_ * hcur;

    // pack lane-pair (jj even/odd, same b) into u32, agent-scope store
    union { bf16_t h; unsigned short u; } cv; cv.h = (bf16_t)hcur;
    const unsigned hv = cv.u;
    const unsigned ov = (unsigned)__shfl_xor((int)hv, 1, 64);
    if ((tid & 1) == 0) {
      const unsigned pk = hv | (ov << 16);
      const size_t widx = ((size_t)b * 128 + t) * 1024 + (jg >> 1);
      __hip_atomic_store(hs32 + widx, pk, __ATOMIC_RELAXED,
                         __HIP_MEMORY_SCOPE_AGENT);
    }

    if (t < 127) {
      // ---- contention-free grid barrier ----
      asm volatile("s_waitcnt vmcnt(0)" ::: "memory");  // hs stores at LLC
      __syncthreads();                                  // whole WG done
      if (tid == 0)
        __hip_atomic_store(arr + (size_t)t * 128 + blockIdx.x, 1u,
                           __ATOMIC_RELAXED, __HIP_MEMORY_SCOPE_AGENT);
      // prefetch xp for t+1: latency hides under the spin
      const int tn = t + 1;
      float xr_n = (float)xp[(size_t)(b * 128 + tn) * 6144 + jg];
      float xz_n = (float)xp[(size_t)(b * 128 + tn) * 6144 + 2048 + jg];
      float xn_n = (float)xp[(size_t)(b * 128 + tn) * 6144 + 4096 + jg];
      asm volatile("" ::: "memory");   // pin prefetch before the spin

      if (wave == 0) {
        const unsigned* f = arr + (size_t)t * 128;
        int guard = 0;
        for (;;) {
          const unsigned a0 = __hip_atomic_load(f + 2 * lane,
              __ATOMIC_RELAXED, __HIP_MEMORY_SCOPE_AGENT);
          const unsigned a1 = __hip_atomic_load(f + 2 * lane + 1,
              __ATOMIC_RELAXED, __HIP_MEMORY_SCOPE_AGENT);
          if (__all(a0 != 0 && a1 != 0)) break;
          __builtin_amdgcn_s_sleep(1);
          if (++guard > (1 << 20)) break;   // safety: never hang
        }
      }
      __syncthreads();   // release WG; hs[t] globally visible

      xr_c = xr_n; xz_c = xz_n; xn_c = xn_n;
    }
  }
}

// ---------------------------------------------------------------------------
// Heads: per (b,t): 3 scalar heads + 4 sigmoid heads, 1024-dot each with a
// label-gathered f32 weight row. out_s is bf16, OUTPUT IS FLOAT32.
// ---------------------------------------------------------------------------
__global__ __launch_bounds__(256) void heads_kernel(
    const bf16_t* __restrict__ out_s, const int* __restrict__ labels,
    const float* __restrict__ W4, const float* __restrict__ b4,
    const float* __restrict__ W5, const float* __restrict__ b5,
    const float* __restrict__ W6, const float* __restrict__ b6,
    const float* __restrict__ Wp, const float* __restrict__ bp,
    float* __restrict__ out)
{
  const int bt  = blockIdx.x;
  const int b   = bt >> 7;         // T = 128
  const int lab = labels[b];
  const bf16_t* os  = out_s + (size_t)bt * 1024;
  const float* w4  = W4 + (size_t)lab * 1024;
  const float* w5  = W5 + (size_t)lab * 1024;
  const float* w6  = W6 + (size_t)lab * 1024;
  const float* wp0 = Wp + (size_t)lab * 1024;   // + p*65536 for plane p

  float s[7] = {0, 0, 0, 0, 0, 0, 0};
  for (int d = threadIdx.x; d < 1024; d += 256) {
    const float v = (float)os[d];
    s[0] += v * w4[d];
    s[1] += v * w5[d];
    s[2] += v * w6[d];
    s[3] += v * wp0[d];
    s[4] += v * wp0[65536 + d];
    s[5] += v * wp0[131072 + d];
    s[6] += v * wp0[196608 + d];
  }
#pragma unroll
  for (int i = 0; i < 7; ++i)
    for (int off = 32; off > 0; off >>= 1)
      s[i] += __shfl_down(s[i], off, 64);

  __shared__ float red[4][7];
  const int lane = threadIdx.x & 63, wave = threadIdx.x >> 6;
  if (lane == 0)
    for (int i = 0; i < 7; ++i) red[wave][i] = s[i];
  __syncthreads();
  if (threadIdx.x == 0) {
    float tsum[7];
    for (int i = 0; i < 7; ++i)
      tsum[i] = red[0][i] + red[1][i] + red[2][i] + red[3][i];
    out[bt]        = tsum[0] + b4[lab];
    out[4096 + bt] = tsum[1] + b5[lab];
    out[8192 + bt] = tsum[2] + b6[lab];
#pragma unroll
    for (int p = 0; p < 4; ++p) {
      const float v = tsum[3 + p] + bp[p * 64 + lab];
      out[12288 + p * 4096 + bt] = 1.0f / (1.0f + __expf(-v));
    }
  }
}

// ---------------------------------------------------------------------------
extern "C" void kernel_launch(void* const* d_in, const int* in_sizes, int n_in,
                              void* d_out, int out_size, void* d_ws, size_t ws_size,
                              hipStream_t stream)
{
  const float* x     = (const float*)d_in[0];
  const int*   label = (const int*)d_in[1];
  const float* W1    = (const float*)d_in[2];
  const float* b1    = (const float*)d_in[3];
  const float* W2    = (const float*)d_in[4];
  const float* b2    = (const float*)d_in[5];
  const float* W_ih  = (const float*)d_in[6];
  const float* b_ih  = (const float*)d_in[7];
  const float* W_hh  = (const float*)d_in[8];
  const float* b_hh  = (const float*)d_in[9];
  const float* W3    = (const float*)d_in[10];
  const float* b3    = (const float*)d_in[11];
  const float* W4    = (const float*)d_in[12];
  const float* b4    = (const float*)d_in[13];
  const float* W5    = (const float*)d_in[14];
  const float* b5    = (const float*)d_in[15];
  const float* W6    = (const float*)d_in[16];
  const float* b6    = (const float*)d_in[17];
  const float* Wp    = (const float*)d_in[18];
  const float* bp    = (const float*)d_in[19];

  // Workspace map (96 MB), bf16 internals:
  //   arr   [0, 64KB)  128x128 u32 per-step arrival flags (memset 0)
  //   out1  [24,32MB)  4096x1024  — dead after layer2
  //   out2  [32,48MB)  4096x2048  — dead after xp GEMM
  //   xp    [48,96MB)  4096x6144  — live through GRU
  //   hs    [24,40MB)  (B,T,2048) — overlays out1+out2-head (dead)
  //   out_s [40,48MB)  4096x1024  — overlays out2 tail (dead)
  char* ws = (char*)d_ws;
  unsigned* arr = (unsigned*)ws;
  bf16_t* out1  = (bf16_t*)(ws + (24u << 20));
  bf16_t* out2  = (bf16_t*)(ws + (32u << 20));
  bf16_t* xp    = (bf16_t*)(ws + (48u << 20));
  bf16_t* hs    = (bf16_t*)(ws + (24u << 20));
  bf16_t* out_s = (bf16_t*)(ws + (40u << 20));
  float*  outp  = (float*)d_out;

  hipMemsetAsync(d_out, 0, (size_t)out_size * sizeof(float), stream);
  hipMemsetAsync(ws, 0, 65536, stream);   // arrival flags

  dim3 blk(256);
  // layer1: (4096x32)*(1024x32)^T, relu
  gemm_bt<float, float><<<dim3(8, 32), blk, 0, stream>>>(x, W1, b1, out1, 4096, 1024, 32, 1);
  // layer2: (4096x1024)*(2048x1024)^T, relu
  gemm_bt<bf16_t, float><<<dim3(16, 32), blk, 0, stream>>>(out1, W2, b2, out2, 4096, 2048, 1024, 1);
  // xp: (4096x2048)*(6144x2048)^T + b_ih
  gemm_bt<bf16_t, float><<<dim3(48, 32), blk, 0, stream>>>(out2, W_ih, b_ih, xp, 4096, 6144, 2048, 0);
  // GRU scan: persistent kernel, register-resident W, flag barrier.
  // Cooperative launch guarantees co-residency of all 128 WGs.
  {
    void* gru_args[] = { (void*)&W_hh, (void*)&b_hh, (void*)&xp, (void*)&hs,
                         (void*)&arr };
    hipLaunchCooperativeKernel((void*)gru_persistent, dim3(128), dim3(512),
                               gru_args, 0, stream);
  }
  // layer3: (4096x2048)*(1024x2048)^T, relu
  gemm_bt<bf16_t, float><<<dim3(8, 32), blk, 0, stream>>>(hs, W3, b3, out_s, 4096, 1024, 2048, 1);
  // heads (f32 weights, f32 out)
  heads_kernel<<<dim3(4096), blk, 0, stream>>>(out_s, label, W4, b4, W5, b5, W6, b6, Wp, bp, outp);
}

// Round 4
// 1439.857 us; speedup vs baseline: 5.6918x; 1.0094x over previous
//
#include <hip/hip_runtime.h>
#include <hip/hip_bf16.h>
#include <math.h>

// B=32, T=128, D_IN=32, H1=1024, H=2048, PEN=1024, C=64, P=4
// Inputs/outputs are FLOAT32 (per the reference dtypes; labels int32).
// Internally: f32 -> bf16 conversion at GEMM staging, bf16 MFMA compute,
// bf16 activations, f32 final outputs. Loose threshold (1.02e-2) admits bf16.

typedef __bf16 bf16_t;
typedef __bf16 bf16x8 __attribute__((ext_vector_type(8)));
typedef float  f32x4  __attribute__((ext_vector_type(4)));

static __device__ __forceinline__ void zero4(f32x4& v) {
  v[0] = 0.0f; v[1] = 0.0f; v[2] = 0.0f; v[3] = 0.0f;
}

template <typename T>
static __device__ __forceinline__ bf16x8 load8_as_bf16(const T* p);
template <>
__device__ __forceinline__ bf16x8 load8_as_bf16<bf16_t>(const bf16_t* p) {
  return *(const bf16x8*)p;
}
template <>
__device__ __forceinline__ bf16x8 load8_as_bf16<float>(const float* p) {
  bf16x8 v;
#pragma unroll
  for (int u = 0; u < 8; ++u) v[u] = (bf16_t)p[u];
  return v;
}

// ---------------------------------------------------------------------------
// GEMM: C[M,N] = act(A[M,K] * Bm[N,K]^T + bias[N]), row-major, bf16 C.
// (unchanged from the 2618us baseline)
// ---------------------------------------------------------------------------
template <typename TA, typename TB>
__global__ __launch_bounds__(256) void gemm_bt(
    const TA* __restrict__ A, const TB* __restrict__ Bm,
    const float* __restrict__ bias, bf16_t* __restrict__ C,
    int M, int N, int K, int relu)
{
  __shared__ __align__(16) bf16_t As[128 * 32];
  __shared__ __align__(16) bf16_t Bs[128 * 32];

  const int tid  = threadIdx.x;
  const int lane = tid & 63;
  const int wave = tid >> 6;
  const int q    = lane >> 4;     // quad 0..3
  const int l15  = lane & 15;
  const int wr   = wave >> 1;     // wave m-half
  const int wc   = wave & 1;      // wave n-half
  const int m0   = blockIdx.y * 128;
  const int n0   = blockIdx.x * 128;

  f32x4 acc[4][4];
#pragma unroll
  for (int i = 0; i < 4; ++i)
#pragma unroll
    for (int j = 0; j < 4; ++j) zero4(acc[i][j]);

  const int se = wave * 512 + lane * 8;  // element in a 2048-elem chunk

  const int kt_count = K >> 5;
  for (int kt = 0; kt < kt_count; ++kt) {
    const int k0 = kt << 5;

    bf16x8 av[2], bv[2];
#pragma unroll
    for (int c = 0; c < 2; ++c) {
      const int e   = c * 2048 + se;
      const int row = e >> 5;      // 0..127
      const int col = e & 31;      // 0,8,16,24
      av[c] = load8_as_bf16<TA>(&A [(size_t)(m0 + row) * K + k0 + col]);
      bv[c] = load8_as_bf16<TB>(&Bm[(size_t)(n0 + row) * K + k0 + col]);
    }

    __syncthreads();   // previous iteration's LDS reads complete
#pragma unroll
    for (int c = 0; c < 2; ++c) {
      *(bf16x8*)&As[c * 2048 + se] = av[c];
      *(bf16x8*)&Bs[c * 2048 + se] = bv[c];
    }
    __syncthreads();   // staging visible to all waves

    bf16x8 af[4], bfv[4];
#pragma unroll
    for (int i = 0; i < 4; ++i)
      af[i] = *(const bf16x8*)&As[(wr * 64 + i * 16 + l15) * 32 + q * 8];
#pragma unroll
    for (int j = 0; j < 4; ++j)
      bfv[j] = *(const bf16x8*)&Bs[(wc * 64 + j * 16 + l15) * 32 + q * 8];

#pragma unroll
    for (int i = 0; i < 4; ++i)
#pragma unroll
      for (int j = 0; j < 4; ++j)
        acc[i][j] = __builtin_amdgcn_mfma_f32_16x16x32_bf16(af[i], bfv[j], acc[i][j], 0, 0, 0);
  }

  // Epilogue: C/D layout col = lane&15 (n), row = (lane>>4)*4 + reg (m)
#pragma unroll
  for (int j = 0; j < 4; ++j) {
    const int n = n0 + wc * 64 + j * 16 + l15;
    const float bvl = bias[n];
#pragma unroll
    for (int i = 0; i < 4; ++i) {
      const int mbase = m0 + wr * 64 + i * 16 + q * 4;
#pragma unroll
      for (int r = 0; r < 4; ++r) {
        float v = acc[i][j][r] + bvl;
        if (relu) v = v > 0.0f ? v : 0.0f;
        C[(size_t)(mbase + r) * N + n] = (bf16_t)v;
      }
    }
  }
}

// ---------------------------------------------------------------------------
// Persistent GRU scan, round 4.
// Round-3 post-mortem: 7.8us/step, MfmaUtil 4% — the serial cross-XCD
// chain (store drain -> flag push -> wave0-only all-flag poll ->
// syncthreads release) dominates; visible work is ~1.5us/step.
// Round-4: PER-WAVE producer polling. Wave w consumes hprev columns
// [256w, 256w+256) == producer WGs 16w..16w+15 EXACTLY (16 flags = one
// 64B line). Each wave polls only its own producer line and proceeds the
// moment those 16 WGs have drained — early waves' loads/MFMA overlap
// late producers' drain+flag push, and the wave0-poll + release-barrier
// hops are gone. Dropping the trailing syncthreads is safe: hp_p[w] for
// t+1 is written only after the post-store syncthreads (A), and all
// step-t reduce reads precede (A).
// Also: ull flag loads (8 lanes x 1 load), fast tanh via __expf (libm
// tanhf's branchy path sat on the serial critical path).
// ---------------------------------------------------------------------------
__global__ __launch_bounds__(512, 2) void gru_persistent(
    const float* __restrict__ W_hh, const float* __restrict__ b_hh,
    const bf16_t* __restrict__ xp, bf16_t* __restrict__ hs,
    unsigned* __restrict__ arr)
{
  __shared__ __align__(16) float hp_p[8][32][52];   // 53,248 B partials

  const int tid  = threadIdx.x;
  const int lane = tid & 63;
  const int wave = tid >> 6;      // K-slice owner, 0..7
  const int q    = lane >> 4;
  const int l15  = lane & 15;
  const int j0   = blockIdx.x * 16;
  const int k0w  = wave * 256;

  // ---- Preload W_hh slice into registers (f32 -> bf16), once ----
  // frag[rt][win]: lane (l15,q): row rt*2048 + j0 + l15 (rt == gate),
  // k = k0w + win*32 + q*8 .. +8
  bf16x8 wf[3][8];
#pragma unroll
  for (int rt = 0; rt < 3; ++rt) {
    const float* rp = W_hh + ((size_t)(rt * 2048 + j0 + l15)) * 2048 + k0w;
#pragma unroll
    for (int win = 0; win < 8; ++win)
      wf[rt][win] = load8_as_bf16<float>(rp + win * 32 + q * 8);
  }

  // pointwise mapping: thread -> (batch b, local col jj)
  const int b  = tid >> 4;        // 0..31
  const int jj = tid & 15;        // 0..15
  const int jg = j0 + jj;
  const float bh_r = b_hh[jg];
  const float bh_z = b_hh[2048 + jg];
  const float bh_n = b_hh[4096 + jg];

  float hcur = 0.0f;              // this thread's own h(b, jg)
  unsigned* hs32 = (unsigned*)hs;

  // xp for t=0
  float xr_c = (float)xp[(size_t)(b * 128 + 0) * 6144 + jg];
  float xz_c = (float)xp[(size_t)(b * 128 + 0) * 6144 + 2048 + jg];
  float xn_c = (float)xp[(size_t)(b * 128 + 0) * 6144 + 4096 + jg];

  for (int t = 0; t < 128; ++t) {
    if (t > 0) {
      // ---- hprev fragment burst: 16 independent 16B loads ----
      bf16x8 bfr[2][8];
#pragma unroll
      for (int ct = 0; ct < 2; ++ct) {
        const bf16_t* bp_ = hs + ((size_t)(ct * 16 + l15) * 128 + (t - 1)) * 2048
                               + k0w + q * 8;
#pragma unroll
        for (int win = 0; win < 8; ++win)
          bfr[ct][win] = *(const bf16x8*)(bp_ + win * 32);
      }

      f32x4 acc[3][2];
#pragma unroll
      for (int rt = 0; rt < 3; ++rt)
#pragma unroll
        for (int ct = 0; ct < 2; ++ct) zero4(acc[rt][ct]);

#pragma unroll
      for (int win = 0; win < 8; ++win)
#pragma unroll
        for (int rt = 0; rt < 3; ++rt)
#pragma unroll
          for (int ct = 0; ct < 2; ++ct)
            acc[rt][ct] = __builtin_amdgcn_mfma_f32_16x16x32_bf16(
                wf[rt][win], bfr[ct][win], acc[rt][ct], 0, 0, 0);

      // partials: D col = l15 (batch within ct-tile), row = q*4+reg (col jj)
#pragma unroll
      for (int rt = 0; rt < 3; ++rt)
#pragma unroll
        for (int ct = 0; ct < 2; ++ct)
          *(f32x4*)&hp_p[wave][ct * 16 + l15][rt * 16 + q * 4] = acc[rt][ct];
    }
    __syncthreads();   // partials visible (and prev-step LDS reuse safe)

    float pr = 0.0f, pz = 0.0f, pn = 0.0f;
    if (t > 0) {
#pragma unroll
      for (int w = 0; w < 8; ++w) {
        pr += hp_p[w][b][jj];
        pz += hp_p[w][b][16 + jj];
        pn += hp_p[w][b][32 + jj];
      }
    }
    const float r_ = 1.0f / (1.0f + __expf(-(xr_c + pr + bh_r)));
    const float z_ = 1.0f / (1.0f + __expf(-(xz_c + pz + bh_z)));
    // fast tanh: tanh(a) = (1 - e^{-2a}) / (1 + e^{-2a})
    const float aa = xn_c + r_ * (pn + bh_n);
    const float et = __expf(-2.0f * aa);
    const float n_ = (1.0f - et) / (1.0f + et);
    hcur = (1.0f - z_) * n_ + z_ * hcur;

    // pack lane-pair (jj even/odd, same b) into u32, agent-scope store
    union { bf16_t h; unsigned short u; } cv; cv.h = (bf16_t)hcur;
    const unsigned hv = cv.u;
    const unsigned ov = (unsigned)__shfl_xor((int)hv, 1, 64);
    if ((tid & 1) == 0) {
      const unsigned pk = hv | (ov << 16);
      const size_t widx = ((size_t)b * 128 + t) * 1024 + (jg >> 1);
      __hip_atomic_store(hs32 + widx, pk, __ATOMIC_RELAXED,
                         __HIP_MEMORY_SCOPE_AGENT);
    }

    if (t < 127) {
      // ---- producer-sliced grid sync ----
      asm volatile("s_waitcnt vmcnt(0)" ::: "memory");  // hs stores at LLC
      __syncthreads();   // (A) whole WG drained; reduces of step t done
      if (tid == 0)
        __hip_atomic_store(arr + (size_t)t * 128 + blockIdx.x, 1u,
                           __ATOMIC_RELAXED, __HIP_MEMORY_SCOPE_AGENT);
      // prefetch xp for t+1: latency hides under the poll
      const int tn = t + 1;
      const float xr_n = (float)xp[(size_t)(b * 128 + tn) * 6144 + jg];
      const float xz_n = (float)xp[(size_t)(b * 128 + tn) * 6144 + 2048 + jg];
      const float xn_n = (float)xp[(size_t)(b * 128 + tn) * 6144 + 4096 + jg];

      // wave w waits only for ITS producers: WGs 16w..16w+15 (one 64B line)
      const unsigned long long* f64p =
          (const unsigned long long*)(arr + (size_t)t * 128) + wave * 8;
      const unsigned long long tgt = 0x0000000100000001ull;
      int guard = 0;
      for (;;) {
        unsigned long long v = tgt;
        if (lane < 8)
          v = __hip_atomic_load(f64p + lane, __ATOMIC_RELAXED,
                                __HIP_MEMORY_SCOPE_AGENT);
        if (__all(v == tgt)) break;
        __builtin_amdgcn_s_sleep(1);
        if (++guard > (1 << 20)) break;   // safety: never hang
      }
      // no trailing syncthreads: each wave proceeds as soon as its
      // producer slice of hs[t] is globally visible.

      xr_c = xr_n; xz_c = xz_n; xn_c = xn_n;
    }
  }
}

// ---------------------------------------------------------------------------
// Heads: per (b,t): 3 scalar heads + 4 sigmoid heads, 1024-dot each with a
// label-gathered f32 weight row. out_s is bf16, OUTPUT IS FLOAT32.
// ---------------------------------------------------------------------------
__global__ __launch_bounds__(256) void heads_kernel(
    const bf16_t* __restrict__ out_s, const int* __restrict__ labels,
    const float* __restrict__ W4, const float* __restrict__ b4,
    const float* __restrict__ W5, const float* __restrict__ b5,
    const float* __restrict__ W6, const float* __restrict__ b6,
    const float* __restrict__ Wp, const float* __restrict__ bp,
    float* __restrict__ out)
{
  const int bt  = blockIdx.x;
  const int b   = bt >> 7;         // T = 128
  const int lab = labels[b];
  const bf16_t* os  = out_s + (size_t)bt * 1024;
  const float* w4  = W4 + (size_t)lab * 1024;
  const float* w5  = W5 + (size_t)lab * 1024;
  const float* w6  = W6 + (size_t)lab * 1024;
  const float* wp0 = Wp + (size_t)lab * 1024;   // + p*65536 for plane p

  float s[7] = {0, 0, 0, 0, 0, 0, 0};
  for (int d = threadIdx.x; d < 1024; d += 256) {
    const float v = (float)os[d];
    s[0] += v * w4[d];
    s[1] += v * w5[d];
    s[2] += v * w6[d];
    s[3] += v * wp0[d];
    s[4] += v * wp0[65536 + d];
    s[5] += v * wp0[131072 + d];
    s[6] += v * wp0[196608 + d];
  }
#pragma unroll
  for (int i = 0; i < 7; ++i)
    for (int off = 32; off > 0; off >>= 1)
      s[i] += __shfl_down(s[i], off, 64);

  __shared__ float red[4][7];
  const int lane = threadIdx.x & 63, wave = threadIdx.x >> 6;
  if (lane == 0)
    for (int i = 0; i < 7; ++i) red[wave][i] = s[i];
  __syncthreads();
  if (threadIdx.x == 0) {
    float tsum[7];
    for (int i = 0; i < 7; ++i)
      tsum[i] = red[0][i] + red[1][i] + red[2][i] + red[3][i];
    out[bt]        = tsum[0] + b4[lab];
    out[4096 + bt] = tsum[1] + b5[lab];
    out[8192 + bt] = tsum[2] + b6[lab];
#pragma unroll
    for (int p = 0; p < 4; ++p) {
      const float v = tsum[3 + p] + bp[p * 64 + lab];
      out[12288 + p * 4096 + bt] = 1.0f / (1.0f + __expf(-v));
    }
  }
}

// ---------------------------------------------------------------------------
extern "C" void kernel_launch(void* const* d_in, const int* in_sizes, int n_in,
                              void* d_out, int out_size, void* d_ws, size_t ws_size,
                              hipStream_t stream)
{
  const float* x     = (const float*)d_in[0];
  const int*   label = (const int*)d_in[1];
  const float* W1    = (const float*)d_in[2];
  const float* b1    = (const float*)d_in[3];
  const float* W2    = (const float*)d_in[4];
  const float* b2    = (const float*)d_in[5];
  const float* W_ih  = (const float*)d_in[6];
  const float* b_ih  = (const float*)d_in[7];
  const float* W_hh  = (const float*)d_in[8];
  const float* b_hh  = (const float*)d_in[9];
  const float* W3    = (const float*)d_in[10];
  const float* b3    = (const float*)d_in[11];
  const float* W4    = (const float*)d_in[12];
  const float* b4    = (const float*)d_in[13];
  const float* W5    = (const float*)d_in[14];
  const float* b5    = (const float*)d_in[15];
  const float* W6    = (const float*)d_in[16];
  const float* b6    = (const float*)d_in[17];
  const float* Wp    = (const float*)d_in[18];
  const float* bp    = (const float*)d_in[19];

  // Workspace map (96 MB), bf16 internals:
  //   arr   [0, 64KB)  128x128 u32 per-step arrival flags (memset 0)
  //   out1  [24,32MB)  4096x1024  — dead after layer2
  //   out2  [32,48MB)  4096x2048  — dead after xp GEMM
  //   xp    [48,96MB)  4096x6144  — live through GRU
  //   hs    [24,40MB)  (B,T,2048) — overlays out1+out2-head (dead)
  //   out_s [40,48MB)  4096x1024  — overlays out2 tail (dead)
  char* ws = (char*)d_ws;
  unsigned* arr = (unsigned*)ws;
  bf16_t* out1  = (bf16_t*)(ws + (24u << 20));
  bf16_t* out2  = (bf16_t*)(ws + (32u << 20));
  bf16_t* xp    = (bf16_t*)(ws + (48u << 20));
  bf16_t* hs    = (bf16_t*)(ws + (24u << 20));
  bf16_t* out_s = (bf16_t*)(ws + (40u << 20));
  float*  outp  = (float*)d_out;

  hipMemsetAsync(d_out, 0, (size_t)out_size * sizeof(float), stream);
  hipMemsetAsync(ws, 0, 65536, stream);   // arrival flags

  dim3 blk(256);
  // layer1: (4096x32)*(1024x32)^T, relu
  gemm_bt<float, float><<<dim3(8, 32), blk, 0, stream>>>(x, W1, b1, out1, 4096, 1024, 32, 1);
  // layer2: (4096x1024)*(2048x1024)^T, relu
  gemm_bt<bf16_t, float><<<dim3(16, 32), blk, 0, stream>>>(out1, W2, b2, out2, 4096, 2048, 1024, 1);
  // xp: (4096x2048)*(6144x2048)^T + b_ih
  gemm_bt<bf16_t, float><<<dim3(48, 32), blk, 0, stream>>>(out2, W_ih, b_ih, xp, 4096, 6144, 2048, 0);
  // GRU scan: persistent kernel, register-resident W, producer-sliced sync.
  // Cooperative launch guarantees co-residency of all 128 WGs.
  {
    void* gru_args[] = { (void*)&W_hh, (void*)&b_hh, (void*)&xp, (void*)&hs,
                         (void*)&arr };
    hipLaunchCooperativeKernel((void*)gru_persistent, dim3(128), dim3(512),
                               gru_args, 0, stream);
  }
  // layer3: (4096x2048)*(1024x2048)^T, relu
  gemm_bt<bf16_t, float><<<dim3(8, 32), blk, 0, stream>>>(hs, W3, b3, out_s, 4096, 1024, 2048, 1);
  // heads (f32 weights, f32 out)
  heads_kernel<<<dim3(4096), blk, 0, stream>>>(out_s, label, W4, b4, W5, b5, W6, b6, Wp, bp, outp);
}